// Round 2
// baseline (4055.590 us; speedup 1.0000x reference)
//
#include <hip/hip_runtime.h>
#include <hip/hip_bf16.h>

// Problem constants
#define BATCH   8192
#define HID     1024
#define HEADS   8
#define OBS4    512      // N_AGENTS*OBS
#define ACT     32
#define A_COLS  128      // N_AGENTS*ACT

// ---------------------------------------------------------------------------
// fp32 GEMM:  C = act(A @ W [+ bias] [+ C_prev])
// A: [M,K] row-major, leading dim lda. W: [K,N] row-major (ld = N = 1024).
// Tile 128x128, BK=16, 256 threads, 8x8 micro-tile.
// ---------------------------------------------------------------------------
template <int RELU, int ACCUM, int BIAS>
__global__ __launch_bounds__(256) void gemm_kernel(
    const float* __restrict__ A, int lda,
    const float* __restrict__ W,
    const float* __restrict__ bias,
    float* __restrict__ C,
    int N, int K)
{
    __shared__ float As[16][128 + 4];   // As[k][m]
    __shared__ float Bs[16][128];       // Bs[k][n]

    const int tid = threadIdx.x;
    const int tx = tid & 15;            // n direction
    const int ty = tid >> 4;            // m direction
    const int m0 = blockIdx.y * 128;
    const int n0 = blockIdx.x * 128;

    float acc[8][8];
#pragma unroll
    for (int i = 0; i < 8; i++)
#pragma unroll
        for (int j = 0; j < 8; j++) acc[i][j] = 0.0f;

    for (int k0 = 0; k0 < K; k0 += 16) {
#pragma unroll
        for (int it = 0; it < 2; it++) {
            const int f   = tid + it * 256;
            const int row = f >> 2;
            const int c4  = f & 3;
            const float4 av = *(const float4*)(A + (long long)(m0 + row) * lda + k0 + c4 * 4);
            As[c4 * 4 + 0][row] = av.x;
            As[c4 * 4 + 1][row] = av.y;
            As[c4 * 4 + 2][row] = av.z;
            As[c4 * 4 + 3][row] = av.w;
        }
#pragma unroll
        for (int it = 0; it < 2; it++) {
            const int f   = tid + it * 256;
            const int row = f >> 5;
            const int c4  = f & 31;
            *(float4*)(&Bs[row][c4 * 4]) =
                *(const float4*)(W + (long long)(k0 + row) * N + n0 + c4 * 4);
        }
        __syncthreads();

#pragma unroll
        for (int k = 0; k < 16; k++) {
            float a_r[8], b_r[8];
#pragma unroll
            for (int i = 0; i < 8; i++) a_r[i] = As[k][ty * 8 + i];
#pragma unroll
            for (int j = 0; j < 8; j++) b_r[j] = Bs[k][tx * 8 + j];
#pragma unroll
            for (int i = 0; i < 8; i++)
#pragma unroll
                for (int j = 0; j < 8; j++)
                    acc[i][j] = fmaf(a_r[i], b_r[j], acc[i][j]);
        }
        __syncthreads();
    }

#pragma unroll
    for (int i = 0; i < 8; i++) {
        const long long m = m0 + ty * 8 + i;
#pragma unroll
        for (int j = 0; j < 8; j += 4) {
            const int n = n0 + tx * 8 + j;
            float4 v;
            v.x = acc[i][j + 0];
            v.y = acc[i][j + 1];
            v.z = acc[i][j + 2];
            v.w = acc[i][j + 3];
            if (BIAS) {
                v.x += bias[n + 0]; v.y += bias[n + 1];
                v.z += bias[n + 2]; v.w += bias[n + 3];
            }
            if (ACCUM) {
                const float4 p = *(const float4*)(C + m * N + n);
                v.x += p.x; v.y += p.y; v.z += p.z; v.w += p.w;
            }
            if (RELU) {
                v.x = fmaxf(v.x, 0.0f); v.y = fmaxf(v.y, 0.0f);
                v.z = fmaxf(v.z, 0.0f); v.w = fmaxf(v.w, 0.0f);
            }
            *(float4*)(C + m * N + n) = v;
        }
    }
}

// ---------------------------------------------------------------------------
// Pass 1: per-head GEMM tile + in-register score dot against decoder_H.
// scores_part[(h*8 + n_tile)][b] = sum over this n-tile of relu(head)*decH
// encoder_heads is NEVER materialized.
// ---------------------------------------------------------------------------
__global__ __launch_bounds__(256) void heads_scores_kernel(
    const float* __restrict__ encH,     // [B, HID]
    const float* __restrict__ decH,     // [B, HID]
    const float* __restrict__ W_heads,  // [H, HID, HID]
    const float* __restrict__ b_heads,  // [H, HID]
    float* __restrict__ scores_part)    // [H*8][B]
{
    __shared__ float As[16][128 + 4];
    __shared__ float Bs[16][128];

    const int h  = blockIdx.z;
    const float* W    = W_heads + (long long)h * HID * HID;
    const float* bias = b_heads + h * HID;

    const int tid = threadIdx.x;
    const int tx = tid & 15;
    const int ty = tid >> 4;
    const int m0 = blockIdx.y * 128;
    const int n0 = blockIdx.x * 128;

    float acc[8][8];
#pragma unroll
    for (int i = 0; i < 8; i++)
#pragma unroll
        for (int j = 0; j < 8; j++) acc[i][j] = 0.0f;

    for (int k0 = 0; k0 < HID; k0 += 16) {
#pragma unroll
        for (int it = 0; it < 2; it++) {
            const int f   = tid + it * 256;
            const int row = f >> 2;
            const int c4  = f & 3;
            const float4 av = *(const float4*)(encH + (long long)(m0 + row) * HID + k0 + c4 * 4);
            As[c4 * 4 + 0][row] = av.x;
            As[c4 * 4 + 1][row] = av.y;
            As[c4 * 4 + 2][row] = av.z;
            As[c4 * 4 + 3][row] = av.w;
        }
#pragma unroll
        for (int it = 0; it < 2; it++) {
            const int f   = tid + it * 256;
            const int row = f >> 5;
            const int c4  = f & 31;
            *(float4*)(&Bs[row][c4 * 4]) =
                *(const float4*)(W + (long long)(k0 + row) * HID + n0 + c4 * 4);
        }
        __syncthreads();

#pragma unroll
        for (int k = 0; k < 16; k++) {
            float a_r[8], b_r[8];
#pragma unroll
            for (int i = 0; i < 8; i++) a_r[i] = As[k][ty * 8 + i];
#pragma unroll
            for (int j = 0; j < 8; j++) b_r[j] = Bs[k][tx * 8 + j];
#pragma unroll
            for (int i = 0; i < 8; i++)
#pragma unroll
                for (int j = 0; j < 8; j++)
                    acc[i][j] = fmaf(a_r[i], b_r[j], acc[i][j]);
        }
        __syncthreads();
    }

    // Epilogue: p[i] = sum_j relu(acc+bias)*decH[row_i][n_j]; reduce over tx.
    float bn[8];
#pragma unroll
    for (int j = 0; j < 8; j++) bn[j] = bias[n0 + tx * 8 + j];

    float p[8];
#pragma unroll
    for (int i = 0; i < 8; i++) {
        const float* dr = decH + (long long)(m0 + ty * 8 + i) * HID + n0 + tx * 8;
        const float4 d0 = *(const float4*)(dr);
        const float4 d1 = *(const float4*)(dr + 4);
        float s = 0.0f;
        s += fmaxf(acc[i][0] + bn[0], 0.0f) * d0.x;
        s += fmaxf(acc[i][1] + bn[1], 0.0f) * d0.y;
        s += fmaxf(acc[i][2] + bn[2], 0.0f) * d0.z;
        s += fmaxf(acc[i][3] + bn[3], 0.0f) * d0.w;
        s += fmaxf(acc[i][4] + bn[4], 0.0f) * d1.x;
        s += fmaxf(acc[i][5] + bn[5], 0.0f) * d1.y;
        s += fmaxf(acc[i][6] + bn[6], 0.0f) * d1.z;
        s += fmaxf(acc[i][7] + bn[7], 0.0f) * d1.w;
        p[i] = s;
    }
    // reduce across the 16 tx lanes (lane bits [3:0] == tx)
#pragma unroll
    for (int off = 1; off < 16; off <<= 1)
#pragma unroll
        for (int i = 0; i < 8; i++) p[i] += __shfl_xor(p[i], off, 64);

    if (tx == 0) {
        float* dst = scores_part + (long long)(h * 8 + blockIdx.x) * BATCH + m0 + ty * 8;
#pragma unroll
        for (int i = 0; i < 8; i++) dst[i] = p[i];
    }
}

// ---------------------------------------------------------------------------
// softmax over heads: attn[b][h] = softmax_h( sum_nt scores_part[h*8+nt][b] )
// ---------------------------------------------------------------------------
__global__ __launch_bounds__(256) void softmax_kernel(
    const float* __restrict__ scores_part, float* __restrict__ attn)
{
    const int b = blockIdx.x * 256 + threadIdx.x;
    float sc[HEADS];
#pragma unroll
    for (int h = 0; h < HEADS; h++) {
        float s = 0.0f;
#pragma unroll
        for (int nt = 0; nt < 8; nt++)
            s += scores_part[(long long)(h * 8 + nt) * BATCH + b];
        sc[h] = s;
    }
    float mx = sc[0];
#pragma unroll
    for (int h = 1; h < HEADS; h++) mx = fmaxf(mx, sc[h]);
    float e[HEADS], sum = 0.0f;
#pragma unroll
    for (int h = 0; h < HEADS; h++) { e[h] = __expf(sc[h] - mx); sum += e[h]; }
    const float inv = 1.0f / sum;
#pragma unroll
    for (int h = 0; h < HEADS; h++) attn[(long long)b * HEADS + h] = e[h] * inv;
}

// ---------------------------------------------------------------------------
// Pass 2: recompute head tiles (h = 0..7) and accumulate context in registers.
// ctx[b][d] = sum_h attn[b][h] * relu(head_h[b][d])
// ---------------------------------------------------------------------------
__global__ __launch_bounds__(256) void heads_context_kernel(
    const float* __restrict__ encH,     // [B, HID]
    const float* __restrict__ W_heads,  // [H, HID, HID]
    const float* __restrict__ b_heads,  // [H, HID]
    const float* __restrict__ attn,     // [B, H]
    float* __restrict__ ctx)            // [B, HID]
{
    __shared__ float As[16][128 + 4];
    __shared__ float Bs[16][128];
    __shared__ float attn_s[128][HEADS];

    const int tid = threadIdx.x;
    const int tx = tid & 15;
    const int ty = tid >> 4;
    const int m0 = blockIdx.y * 128;
    const int n0 = blockIdx.x * 128;

    // stage attn for this m-tile: 128 rows x 8 = 1024 floats = 256 float4
    *(float4*)(&attn_s[tid >> 1][(tid & 1) * 4]) =
        *(const float4*)(attn + (long long)(m0 + (tid >> 1)) * HEADS + (tid & 1) * 4);

    float ctxa[8][8];
#pragma unroll
    for (int i = 0; i < 8; i++)
#pragma unroll
        for (int j = 0; j < 8; j++) ctxa[i][j] = 0.0f;

    for (int h = 0; h < HEADS; h++) {
        const float* W    = W_heads + (long long)h * HID * HID;
        const float* bias = b_heads + h * HID;

        float acc[8][8];
#pragma unroll
        for (int i = 0; i < 8; i++)
#pragma unroll
            for (int j = 0; j < 8; j++) acc[i][j] = 0.0f;

        for (int k0 = 0; k0 < HID; k0 += 16) {
#pragma unroll
            for (int it = 0; it < 2; it++) {
                const int f   = tid + it * 256;
                const int row = f >> 2;
                const int c4  = f & 3;
                const float4 av = *(const float4*)(encH + (long long)(m0 + row) * HID + k0 + c4 * 4);
                As[c4 * 4 + 0][row] = av.x;
                As[c4 * 4 + 1][row] = av.y;
                As[c4 * 4 + 2][row] = av.z;
                As[c4 * 4 + 3][row] = av.w;
            }
#pragma unroll
            for (int it = 0; it < 2; it++) {
                const int f   = tid + it * 256;
                const int row = f >> 5;
                const int c4  = f & 31;
                *(float4*)(&Bs[row][c4 * 4]) =
                    *(const float4*)(W + (long long)(k0 + row) * HID + n0 + c4 * 4);
            }
            __syncthreads();

#pragma unroll
            for (int k = 0; k < 16; k++) {
                float a_r[8], b_r[8];
#pragma unroll
                for (int i = 0; i < 8; i++) a_r[i] = As[k][ty * 8 + i];
#pragma unroll
                for (int j = 0; j < 8; j++) b_r[j] = Bs[k][tx * 8 + j];
#pragma unroll
                for (int i = 0; i < 8; i++)
#pragma unroll
                    for (int j = 0; j < 8; j++)
                        acc[i][j] = fmaf(a_r[i], b_r[j], acc[i][j]);
            }
            __syncthreads();
        }

        float bn[8];
#pragma unroll
        for (int j = 0; j < 8; j++) bn[j] = bias[n0 + tx * 8 + j];
#pragma unroll
        for (int i = 0; i < 8; i++) {
            const float w = attn_s[ty * 8 + i][h];
#pragma unroll
            for (int j = 0; j < 8; j++)
                ctxa[i][j] = fmaf(w, fmaxf(acc[i][j] + bn[j], 0.0f), ctxa[i][j]);
        }
    }

#pragma unroll
    for (int i = 0; i < 8; i++) {
        const long long m = m0 + ty * 8 + i;
#pragma unroll
        for (int j = 0; j < 8; j += 4) {
            const int n = n0 + tx * 8 + j;
            float4 v;
            v.x = ctxa[i][j + 0]; v.y = ctxa[i][j + 1];
            v.z = ctxa[i][j + 2]; v.w = ctxa[i][j + 3];
            *(float4*)(ctx + m * HID + n) = v;
        }
    }
}

// ---------------------------------------------------------------------------
// fc2: q[b] = sum_d x[b,d]*W2[d] + b2[0]
// ---------------------------------------------------------------------------
__global__ __launch_bounds__(256) void fc2_kernel(
    const float* __restrict__ x, const float* __restrict__ W2,
    const float* __restrict__ b2, float* __restrict__ q)
{
    const int b   = blockIdx.x;
    const int tid = threadIdx.x;
    __shared__ float red[4];

    const float4 xv = *(const float4*)(x + (long long)b * HID + tid * 4);
    const float4 wv = *(const float4*)(W2 + tid * 4);
    float p = xv.x * wv.x + xv.y * wv.y + xv.z * wv.z + xv.w * wv.w;
#pragma unroll
    for (int off = 32; off > 0; off >>= 1) p += __shfl_down(p, off, 64);
    if ((tid & 63) == 0) red[tid >> 6] = p;
    __syncthreads();
    if (tid == 0) q[b] = red[0] + red[1] + red[2] + red[3] + b2[0];
}

// ---------------------------------------------------------------------------
extern "C" void kernel_launch(void* const* d_in, const int* in_sizes, int n_in,
                              void* d_out, int out_size, void* d_ws, size_t ws_size,
                              hipStream_t stream)
{
    const float* s        = (const float*)d_in[0];
    const float* a        = (const float*)d_in[1];
    const float* W_enc_in = (const float*)d_in[2];
    const float* b_enc_in = (const float*)d_in[3];
    const float* W_dec_in = (const float*)d_in[4];
    const float* b_dec_in = (const float*)d_in[5];
    const float* W_eh     = (const float*)d_in[6];
    const float* b_eh     = (const float*)d_in[7];
    const float* W_heads  = (const float*)d_in[8];
    const float* b_heads  = (const float*)d_in[9];
    const float* W_dh     = (const float*)d_in[10];
    const float* b_dh     = (const float*)d_in[11];
    const float* W1       = (const float*)d_in[12];
    const float* b1       = (const float*)d_in[13];
    const float* W2       = (const float*)d_in[14];
    const float* b2       = (const float*)d_in[15];
    float* q_out = (float*)d_out;

    // Workspace: 3 ping-pong activation buffers + score partials + attn
    // total = 3*B*HID + 64*B + 8*B floats  ~= 103 MB
    const long long SZ = (long long)BATCH * HID;
    float* bufA        = (float*)d_ws;          // enc_input / dec_input / context
    float* bufB        = bufA + SZ;             // encoder_h
    float* bufC        = bufB + SZ;             // decoder_H / x
    float* scores_part = bufC + SZ;             // [64][B]
    float* attn        = scores_part + 64LL * BATCH;  // [B][8]

    const dim3 blk(256);
    const dim3 gg(HID / 128, BATCH / 128, 1);
    const dim3 gh(HID / 128, BATCH / 128, HEADS);

    // 1. enc_input = s @ W_enc_in[0:512]                       -> bufA
    gemm_kernel<0, 0, 0><<<gg, blk, 0, stream>>>(
        s, OBS4, W_enc_in, nullptr, bufA, HID, OBS4);
    // 2. enc_input += a[:, :32] @ W_enc_in[512:544] + b_enc_in -> bufA
    gemm_kernel<0, 1, 1><<<gg, blk, 0, stream>>>(
        a, A_COLS, W_enc_in + (long long)OBS4 * HID, b_enc_in, bufA, HID, ACT);
    // 3. encoder_h = relu(enc_input @ W_eh + b_eh)             -> bufB
    gemm_kernel<1, 0, 1><<<gg, blk, 0, stream>>>(
        bufA, HID, W_eh, b_eh, bufB, HID, HID);
    // 4. dec_input = a[:, 32:] @ W_dec_in + b_dec_in           -> bufA
    gemm_kernel<0, 0, 1><<<gg, blk, 0, stream>>>(
        a + ACT, A_COLS, W_dec_in, b_dec_in, bufA, HID, 96);
    // 5. decoder_H = relu(dec_input @ W_dh + b_dh)             -> bufC
    gemm_kernel<1, 0, 1><<<gg, blk, 0, stream>>>(
        bufA, HID, W_dh, b_dh, bufC, HID, HID);
    // 6. scores (heads fused, not materialized)
    heads_scores_kernel<<<gh, blk, 0, stream>>>(
        bufB, bufC, W_heads, b_heads, scores_part);
    // 7. softmax
    softmax_kernel<<<dim3(BATCH / 256), blk, 0, stream>>>(scores_part, attn);
    // 8. context (heads recomputed, weighted in registers)     -> bufA
    heads_context_kernel<<<gg, blk, 0, stream>>>(
        bufB, W_heads, b_heads, attn, bufA);
    // 9. x = relu(context @ W1 + b1)                           -> bufC
    gemm_kernel<1, 0, 1><<<gg, blk, 0, stream>>>(
        bufA, HID, W1, b1, bufC, HID, HID);
    // 10. q = x @ W2 + b2                                      -> d_out
    fc2_kernel<<<dim3(BATCH), blk, 0, stream>>>(bufC, W2, b2, q_out);
}

// Round 3
// 961.165 us; speedup vs baseline: 4.2195x; 4.2195x over previous
//
#include <hip/hip_runtime.h>
#include <hip/hip_bf16.h>
#include <hip/hip_fp16.h>

// Problem constants
#define BATCH   8192
#define HID     1024
#define HEADS   8
#define OBS4    512      // N_AGENTS*OBS
#define ACT     32
#define BC      2048     // heads-section batch chunk
#define NCHUNK  (BATCH / BC)

typedef __attribute__((ext_vector_type(8))) short bf16x8;
typedef __attribute__((ext_vector_type(4))) float f32x4;

// ---------------------------------------------------------------------------
// hi/lo split (truncation both): x = hi + lo + O(2^-16 |x|)
// pack 2 floats' top-16 bits into one uint (low short = first elem).
// ---------------------------------------------------------------------------
__device__ __forceinline__ uint pack_hi2(uint u0, uint u1) {
    return (u0 >> 16) | (u1 & 0xFFFF0000u);
}

__device__ __forceinline__ void splitA4(float4 v, uint2& hi, uint2& lo) {
    uint u0 = __float_as_uint(v.x), u1 = __float_as_uint(v.y),
         u2 = __float_as_uint(v.z), u3 = __float_as_uint(v.w);
    float r0 = v.x - __uint_as_float(u0 & 0xFFFF0000u);
    float r1 = v.y - __uint_as_float(u1 & 0xFFFF0000u);
    float r2 = v.z - __uint_as_float(u2 & 0xFFFF0000u);
    float r3 = v.w - __uint_as_float(u3 & 0xFFFF0000u);
    hi.x = pack_hi2(u0, u1);
    hi.y = pack_hi2(u2, u3);
    lo.x = pack_hi2(__float_as_uint(r0), __float_as_uint(r1));
    lo.y = pack_hi2(__float_as_uint(r2), __float_as_uint(r3));
}

// ---------------------------------------------------------------------------
// Split-bf16 MFMA GEMM:  C = act(A @ W + bias),  N fixed = 1024.
// A fp32 [M][K] (row-major, lda); columns >= ksplit come from A2 (lda2) —
// used to fuse the s|a concat. W fp32 [K][1024]. 128x128 tile, BK=32,
// 256 threads = 4 waves, each wave 64x64 via 4x4 grid of 16x16x32 MFMAs,
// 3 MFMAs per pair (hi*hi + hi*lo + lo*hi).
// ---------------------------------------------------------------------------
template <int RELU>
__global__ __launch_bounds__(256) void gemm_split(
    const float* __restrict__ A, int lda,
    const float* __restrict__ A2, int lda2, int ksplit,
    const float* __restrict__ W,
    const float* __restrict__ bias,
    float* __restrict__ C, int K)
{
    __shared__ short Ah[128 * 40];   // [m][k] stride 40 shorts (80 B)
    __shared__ short Al[128 * 40];
    __shared__ short Bh[128 * 40];   // [n][k] stride 40
    __shared__ short Bl[128 * 40];

    const int tid  = threadIdx.x;
    const int lane = tid & 63;
    const int wv   = tid >> 6;
    const int wm   = wv >> 1, wn = wv & 1;
    const int fr   = lane & 15;      // row (A) / col (B) in 16-tile
    const int fq   = lane >> 4;      // quad -> k-offset fq*8 / acc row fq*4
    const int m0   = blockIdx.y * 128;
    const int n0   = blockIdx.x * 128;

    // staging maps
    const int ar  = tid >> 3;        // A: rows 0..31 (+32*it)
    const int akq = tid & 7;         // A: float4 col group
    const int bn  = tid & 127;       // B: n
    const int bkh = (tid >> 7) * 16; // B: k half

    f32x4 acc[4][4];
#pragma unroll
    for (int i = 0; i < 4; i++)
#pragma unroll
        for (int j = 0; j < 4; j++) acc[i][j] = 0;

    for (int k0 = 0; k0 < K; k0 += 32) {
        // ---- select A source (concat fusion) -- uniform per k0
        const float* src; int sl, kc;
        if (k0 < ksplit) { src = A;  sl = lda;  kc = k0; }
        else             { src = A2; sl = lda2; kc = k0 - ksplit; }

        // ---- stage A: 128x32 fp32 -> hi/lo bf16 LDS
#pragma unroll
        for (int it = 0; it < 4; it++) {
            const int row = ar + it * 32;
            const float4 v = *(const float4*)(src + (long long)(m0 + row) * sl + kc + akq * 4);
            uint2 hi, lo;
            splitA4(v, hi, lo);
            *(uint2*)&Ah[row * 40 + akq * 4] = hi;
            *(uint2*)&Al[row * 40 + akq * 4] = lo;
        }
        // ---- stage B (transpose): 32x128 fp32 -> [n][k] hi/lo LDS
        {
            const float* wp = W + (long long)(k0 + bkh) * 1024 + n0 + bn;
            uint h[8], l[8];
#pragma unroll
            for (int p = 0; p < 8; p++) {
                const float x0 = wp[(2 * p) * 1024];
                const float x1 = wp[(2 * p + 1) * 1024];
                const uint u0 = __float_as_uint(x0), u1 = __float_as_uint(x1);
                const float r0 = x0 - __uint_as_float(u0 & 0xFFFF0000u);
                const float r1 = x1 - __uint_as_float(u1 & 0xFFFF0000u);
                h[p] = pack_hi2(u0, u1);
                l[p] = pack_hi2(__float_as_uint(r0), __float_as_uint(r1));
            }
            uint4 v4;
            v4.x = h[0]; v4.y = h[1]; v4.z = h[2]; v4.w = h[3];
            *(uint4*)&Bh[bn * 40 + bkh] = v4;
            v4.x = h[4]; v4.y = h[5]; v4.z = h[6]; v4.w = h[7];
            *(uint4*)&Bh[bn * 40 + bkh + 8] = v4;
            v4.x = l[0]; v4.y = l[1]; v4.z = l[2]; v4.w = l[3];
            *(uint4*)&Bl[bn * 40 + bkh] = v4;
            v4.x = l[4]; v4.y = l[5]; v4.z = l[6]; v4.w = l[7];
            *(uint4*)&Bl[bn * 40 + bkh + 8] = v4;
        }
        __syncthreads();

        // ---- fragments + 48 MFMAs
        bf16x8 ah[4], al[4], bh[4], bl[4];
#pragma unroll
        for (int i = 0; i < 4; i++) {
            const int off = (wm * 64 + i * 16 + fr) * 40 + fq * 8;
            ah[i] = *(bf16x8*)&Ah[off];
            al[i] = *(bf16x8*)&Al[off];
        }
#pragma unroll
        for (int j = 0; j < 4; j++) {
            const int off = (wn * 64 + j * 16 + fr) * 40 + fq * 8;
            bh[j] = *(bf16x8*)&Bh[off];
            bl[j] = *(bf16x8*)&Bl[off];
        }
#pragma unroll
        for (int i = 0; i < 4; i++)
#pragma unroll
            for (int j = 0; j < 4; j++) {
                acc[i][j] = __builtin_amdgcn_mfma_f32_16x16x32_bf16(ah[i], bh[j], acc[i][j], 0, 0, 0);
                acc[i][j] = __builtin_amdgcn_mfma_f32_16x16x32_bf16(ah[i], bl[j], acc[i][j], 0, 0, 0);
                acc[i][j] = __builtin_amdgcn_mfma_f32_16x16x32_bf16(al[i], bh[j], acc[i][j], 0, 0, 0);
            }
        __syncthreads();
    }

    // ---- epilogue: bias (+relu), scalar stores (C/D: col=fr, row=fq*4+r)
#pragma unroll
    for (int j = 0; j < 4; j++) {
        const int n = n0 + wn * 64 + j * 16 + fr;
        const float bb = bias[n];
#pragma unroll
        for (int i = 0; i < 4; i++) {
#pragma unroll
            for (int r = 0; r < 4; r++) {
                const int m = m0 + wm * 64 + i * 16 + fq * 4 + r;
                float v = acc[i][j][r] + bb;
                if (RELU) v = fmaxf(v, 0.0f);
                C[(long long)m * 1024 + n] = v;
            }
        }
    }
}

// ---------------------------------------------------------------------------
// Heads pass (per chunk, z = head): same split GEMM core; epilogue writes
// relu(head) as fp16 to headsb AND the partial score dot vs decH.
// scoresp[(h*8 + nblock)][BC]
// ---------------------------------------------------------------------------
__global__ __launch_bounds__(256) void heads_kernel(
    const float* __restrict__ encH,     // chunk-offset [BC][1024]
    const float* __restrict__ decH,     // chunk-offset [BC][1024]
    const float* __restrict__ W_heads,  // [H][1024][1024]
    const float* __restrict__ b_heads,  // [H][1024]
    __half* __restrict__ headsb,        // [BC][H][1024]
    float* __restrict__ scoresp)        // [H*8][BC]
{
    __shared__ short Ah[128 * 40];
    __shared__ short Al[128 * 40];
    __shared__ short Bh[128 * 40];
    __shared__ short Bl[128 * 40];
    __shared__ float scred[2][128];

    const int h = blockIdx.z;
    const float* W    = W_heads + (long long)h * 1024 * 1024;
    const float* bias = b_heads + h * 1024;

    const int tid  = threadIdx.x;
    const int lane = tid & 63;
    const int wv   = tid >> 6;
    const int wm   = wv >> 1, wn = wv & 1;
    const int fr   = lane & 15;
    const int fq   = lane >> 4;
    const int m0   = blockIdx.y * 128;
    const int n0   = blockIdx.x * 128;

    const int ar  = tid >> 3;
    const int akq = tid & 7;
    const int bn  = tid & 127;
    const int bkh = (tid >> 7) * 16;

    f32x4 acc[4][4];
#pragma unroll
    for (int i = 0; i < 4; i++)
#pragma unroll
        for (int j = 0; j < 4; j++) acc[i][j] = 0;

    for (int k0 = 0; k0 < 1024; k0 += 32) {
#pragma unroll
        for (int it = 0; it < 4; it++) {
            const int row = ar + it * 32;
            const float4 v = *(const float4*)(encH + (long long)(m0 + row) * 1024 + k0 + akq * 4);
            uint2 hi, lo;
            splitA4(v, hi, lo);
            *(uint2*)&Ah[row * 40 + akq * 4] = hi;
            *(uint2*)&Al[row * 40 + akq * 4] = lo;
        }
        {
            const float* wp = W + (long long)(k0 + bkh) * 1024 + n0 + bn;
            uint hh[8], ll[8];
#pragma unroll
            for (int p = 0; p < 8; p++) {
                const float x0 = wp[(2 * p) * 1024];
                const float x1 = wp[(2 * p + 1) * 1024];
                const uint u0 = __float_as_uint(x0), u1 = __float_as_uint(x1);
                const float r0 = x0 - __uint_as_float(u0 & 0xFFFF0000u);
                const float r1 = x1 - __uint_as_float(u1 & 0xFFFF0000u);
                hh[p] = pack_hi2(u0, u1);
                ll[p] = pack_hi2(__float_as_uint(r0), __float_as_uint(r1));
            }
            uint4 v4;
            v4.x = hh[0]; v4.y = hh[1]; v4.z = hh[2]; v4.w = hh[3];
            *(uint4*)&Bh[bn * 40 + bkh] = v4;
            v4.x = hh[4]; v4.y = hh[5]; v4.z = hh[6]; v4.w = hh[7];
            *(uint4*)&Bh[bn * 40 + bkh + 8] = v4;
            v4.x = ll[0]; v4.y = ll[1]; v4.z = ll[2]; v4.w = ll[3];
            *(uint4*)&Bl[bn * 40 + bkh] = v4;
            v4.x = ll[4]; v4.y = ll[5]; v4.z = ll[6]; v4.w = ll[7];
            *(uint4*)&Bl[bn * 40 + bkh + 8] = v4;
        }
        __syncthreads();

        bf16x8 ah[4], al[4], bh[4], bl[4];
#pragma unroll
        for (int i = 0; i < 4; i++) {
            const int off = (wm * 64 + i * 16 + fr) * 40 + fq * 8;
            ah[i] = *(bf16x8*)&Ah[off];
            al[i] = *(bf16x8*)&Al[off];
        }
#pragma unroll
        for (int j = 0; j < 4; j++) {
            const int off = (wn * 64 + j * 16 + fr) * 40 + fq * 8;
            bh[j] = *(bf16x8*)&Bh[off];
            bl[j] = *(bf16x8*)&Bl[off];
        }
#pragma unroll
        for (int i = 0; i < 4; i++)
#pragma unroll
            for (int j = 0; j < 4; j++) {
                acc[i][j] = __builtin_amdgcn_mfma_f32_16x16x32_bf16(ah[i], bh[j], acc[i][j], 0, 0, 0);
                acc[i][j] = __builtin_amdgcn_mfma_f32_16x16x32_bf16(ah[i], bl[j], acc[i][j], 0, 0, 0);
                acc[i][j] = __builtin_amdgcn_mfma_f32_16x16x32_bf16(al[i], bh[j], acc[i][j], 0, 0, 0);
            }
        __syncthreads();
    }

    // ---- epilogue: relu(acc+bias) -> fp16 heads, partial scores vs decH
    float part[4][4];
#pragma unroll
    for (int i = 0; i < 4; i++)
#pragma unroll
        for (int r = 0; r < 4; r++) part[i][r] = 0.0f;

#pragma unroll
    for (int j = 0; j < 4; j++) {
        const int n = n0 + wn * 64 + j * 16 + fr;
        const float bb = bias[n];
#pragma unroll
        for (int i = 0; i < 4; i++) {
#pragma unroll
            for (int r = 0; r < 4; r++) {
                const int b_loc = m0 + wm * 64 + i * 16 + fq * 4 + r;
                float v = fmaxf(acc[i][j][r] + bb, 0.0f);
                headsb[((long long)b_loc * HEADS + h) * 1024 + n] = __float2half(v);
                part[i][r] = fmaf(v, decH[(long long)b_loc * 1024 + n], part[i][r]);
            }
        }
    }
    // reduce across the 16 fr lanes
#pragma unroll
    for (int off = 1; off < 16; off <<= 1)
#pragma unroll
        for (int i = 0; i < 4; i++)
#pragma unroll
            for (int r = 0; r < 4; r++)
                part[i][r] += __shfl_xor(part[i][r], off, 64);

    if (fr == 0) {
#pragma unroll
        for (int i = 0; i < 4; i++)
#pragma unroll
            for (int r = 0; r < 4; r++)
                scred[wn][wm * 64 + i * 16 + fq * 4 + r] = part[i][r];
    }
    __syncthreads();
    if (tid < 128) {
        const float s = scred[0][tid] + scred[1][tid];
        scoresp[(long long)(h * 8 + blockIdx.x) * BC + m0 + tid] = s;
    }
}

// ---------------------------------------------------------------------------
// softmax over heads (per chunk): attn[b][h] = softmax_h(sum_nt scoresp)
// ---------------------------------------------------------------------------
__global__ __launch_bounds__(256) void softmax_kernel(
    const float* __restrict__ scoresp, float* __restrict__ attn)
{
    const int b = blockIdx.x * 256 + threadIdx.x;    // 0..BC-1
    float sc[HEADS];
#pragma unroll
    for (int h = 0; h < HEADS; h++) {
        float s = 0.0f;
#pragma unroll
        for (int nt = 0; nt < 8; nt++)
            s += scoresp[(long long)(h * 8 + nt) * BC + b];
        sc[h] = s;
    }
    float mx = sc[0];
#pragma unroll
    for (int h = 1; h < HEADS; h++) mx = fmaxf(mx, sc[h]);
    float e[HEADS], sum = 0.0f;
#pragma unroll
    for (int h = 0; h < HEADS; h++) { e[h] = __expf(sc[h] - mx); sum += e[h]; }
    const float inv = 1.0f / sum;
#pragma unroll
    for (int h = 0; h < HEADS; h++) attn[(long long)b * HEADS + h] = e[h] * inv;
}

// ---------------------------------------------------------------------------
// context (per chunk): ctx[b][d] = sum_h attn[b][h] * heads_fp16[b][h][d]
// one block per row.
// ---------------------------------------------------------------------------
__global__ __launch_bounds__(256) void context_kernel(
    const __half* __restrict__ headsb, const float* __restrict__ attn,
    float* __restrict__ ctx)
{
    const int b = blockIdx.x;
    const int d = threadIdx.x * 4;
    float w[HEADS];
#pragma unroll
    for (int h = 0; h < HEADS; h++) w[h] = attn[(long long)b * HEADS + h];
    float4 acc = make_float4(0.f, 0.f, 0.f, 0.f);
#pragma unroll
    for (int h = 0; h < HEADS; h++) {
        const __half2* hp = (const __half2*)(headsb + ((long long)b * HEADS + h) * 1024 + d);
        const float2 f0 = __half22float2(hp[0]);
        const float2 f1 = __half22float2(hp[1]);
        acc.x = fmaf(w[h], f0.x, acc.x);
        acc.y = fmaf(w[h], f0.y, acc.y);
        acc.z = fmaf(w[h], f1.x, acc.z);
        acc.w = fmaf(w[h], f1.y, acc.w);
    }
    *(float4*)(ctx + (long long)b * 1024 + d) = acc;
}

// ---------------------------------------------------------------------------
// fc2: q[b] = sum_d x[b,d]*W2[d] + b2[0]
// ---------------------------------------------------------------------------
__global__ __launch_bounds__(256) void fc2_kernel(
    const float* __restrict__ x, const float* __restrict__ W2,
    const float* __restrict__ b2, float* __restrict__ q)
{
    const int b   = blockIdx.x;
    const int tid = threadIdx.x;
    __shared__ float red[4];

    const float4 xv = *(const float4*)(x + (long long)b * 1024 + tid * 4);
    const float4 wv = *(const float4*)(W2 + tid * 4);
    float p = xv.x * wv.x + xv.y * wv.y + xv.z * wv.z + xv.w * wv.w;
#pragma unroll
    for (int off = 32; off > 0; off >>= 1) p += __shfl_down(p, off, 64);
    if ((tid & 63) == 0) red[tid >> 6] = p;
    __syncthreads();
    if (tid == 0) q[b] = red[0] + red[1] + red[2] + red[3] + b2[0];
}

// ---------------------------------------------------------------------------
extern "C" void kernel_launch(void* const* d_in, const int* in_sizes, int n_in,
                              void* d_out, int out_size, void* d_ws, size_t ws_size,
                              hipStream_t stream)
{
    const float* s        = (const float*)d_in[0];
    const float* a        = (const float*)d_in[1];
    const float* W_enc_in = (const float*)d_in[2];
    const float* b_enc_in = (const float*)d_in[3];
    const float* W_dec_in = (const float*)d_in[4];
    const float* b_dec_in = (const float*)d_in[5];
    const float* W_eh     = (const float*)d_in[6];
    const float* b_eh     = (const float*)d_in[7];
    const float* W_heads  = (const float*)d_in[8];
    const float* b_heads  = (const float*)d_in[9];
    const float* W_dh     = (const float*)d_in[10];
    const float* b_dh     = (const float*)d_in[11];
    const float* W1       = (const float*)d_in[12];
    const float* b1       = (const float*)d_in[13];
    const float* W2       = (const float*)d_in[14];
    const float* b2       = (const float*)d_in[15];
    float* q_out = (float*)d_out;

    // Workspace (~99.7 MB, <= 103 MB known-good):
    //   [encH 8M floats | decH 8M | free: bufA(8M) then heads(BC*8*1024 fp16)
    //    + scoresp(64*BC) + attn(BC*8)]
    // ctx overwrites encH rows per-chunk; x overwrites decH.
    const long long SZ = (long long)BATCH * HID;      // 8M
    float* encH  = (float*)d_ws;
    float* decH  = encH + SZ;
    float* freeR = decH + SZ;
    float* bufA  = freeR;
    __half* headsb = (__half*)freeR;
    float* scoresp = freeR + ((long long)BC * HEADS * 1024 / 2);
    float* attnb   = scoresp + 64LL * BC;

    const dim3 blk(256);
    const dim3 gg(8, BATCH / 128, 1);
    const dim3 ghc(8, BC / 128, HEADS);
    const int KBIG = 1 << 28;   // ksplit sentinel: never use A2

    // 1. enc_input = [s | a[:, :32]] @ W_enc + b  (concat fused) -> bufA
    gemm_split<0><<<gg, blk, 0, stream>>>(s, OBS4, a, 128, OBS4,
                                          W_enc_in, b_enc_in, bufA, 544);
    // 2. encoder_h = relu(enc_input @ W_eh + b_eh) -> encH
    gemm_split<1><<<gg, blk, 0, stream>>>(bufA, HID, bufA, HID, KBIG,
                                          W_eh, b_eh, encH, 1024);
    // 3. dec_input = a[:, 32:] @ W_dec + b -> bufA
    gemm_split<0><<<gg, blk, 0, stream>>>(a + ACT, 128, a + ACT, 128, KBIG,
                                          W_dec_in, b_dec_in, bufA, 96);
    // 4. decoder_H = relu(dec_input @ W_dh + b_dh) -> decH
    gemm_split<1><<<gg, blk, 0, stream>>>(bufA, HID, bufA, HID, KBIG,
                                          W_dh, b_dh, decH, 1024);
    // 5. heads section, chunked (bufA dead from here)
    for (int c = 0; c < NCHUNK; c++) {
        const long long off = (long long)c * BC * 1024;
        heads_kernel<<<ghc, blk, 0, stream>>>(encH + off, decH + off,
                                              W_heads, b_heads, headsb, scoresp);
        softmax_kernel<<<dim3(BC / 256), blk, 0, stream>>>(scoresp, attnb);
        // ctx chunk overwrites encH chunk rows (dead after this chunk's scores)
        context_kernel<<<dim3(BC), blk, 0, stream>>>(headsb, attnb, encH + off);
    }
    // 6. x = relu(ctx @ W1 + b1) -> decH (dead)
    gemm_split<1><<<gg, blk, 0, stream>>>(encH, HID, encH, HID, KBIG,
                                          W1, b1, decH, 1024);
    // 7. q = x @ W2 + b2 -> out
    fc2_kernel<<<dim3(BATCH), blk, 0, stream>>>(decH, W2, b2, q_out);
}

// Round 4
// 868.026 us; speedup vs baseline: 4.6722x; 1.1073x over previous
//
#include <hip/hip_runtime.h>
#include <hip/hip_bf16.h>
#include <hip/hip_fp16.h>

#define BATCH   8192
#define HID     1024
#define HEADS   8
#define BC      2048

typedef unsigned int  u32;
typedef unsigned short u16;
typedef __attribute__((ext_vector_type(8))) short bf16x8;
typedef __attribute__((ext_vector_type(4))) float f32x4;

// ---------------------------------------------------------------------------
// hi/lo split helpers (truncation both; x = hi + lo + O(2^-16 |x|))
// ---------------------------------------------------------------------------
__device__ __forceinline__ u32 pack_hi2(u32 u0, u32 u1) {
    return (u0 >> 16) | (u1 & 0xFFFF0000u);
}
__device__ __forceinline__ void split1(float x, u16& h, u16& l) {
    const u32 u = __float_as_uint(x);
    h = (u16)(u >> 16);
    const float r = x - __uint_as_float(u & 0xFFFF0000u);
    l = (u16)(__float_as_uint(r) >> 16);
}
__device__ __forceinline__ void splitA4(float4 v, uint2& hi, uint2& lo) {
    u32 u0 = __float_as_uint(v.x), u1 = __float_as_uint(v.y),
        u2 = __float_as_uint(v.z), u3 = __float_as_uint(v.w);
    float r0 = v.x - __uint_as_float(u0 & 0xFFFF0000u);
    float r1 = v.y - __uint_as_float(u1 & 0xFFFF0000u);
    float r2 = v.z - __uint_as_float(u2 & 0xFFFF0000u);
    float r3 = v.w - __uint_as_float(u3 & 0xFFFF0000u);
    hi.x = pack_hi2(u0, u1);
    hi.y = pack_hi2(u2, u3);
    lo.x = pack_hi2(__float_as_uint(r0), __float_as_uint(r1));
    lo.y = pack_hi2(__float_as_uint(r2), __float_as_uint(r3));
}

// ---------------------------------------------------------------------------
// Weight conversion: W fp32 [K][1024] (z-batched) -> hi/lo bf16 planes in
// k-tiled transposed layout  Wt[kt][n][32]  (kt = k/32).
// ---------------------------------------------------------------------------
__global__ __launch_bounds__(256) void split_weight_kernel(
    const float* __restrict__ W, u16* __restrict__ hi, u16* __restrict__ lo,
    int K)
{
    const long long zoff = (long long)blockIdx.z * K * 1024;
    const int kt  = blockIdx.x;
    const int n0  = blockIdx.y * 128;
    const int tid = threadIdx.x;
    const int k   = tid >> 3;            // 0..31
    const int ng  = (tid & 7) * 16;      // 0,16,...,112
    const float* src = W + zoff + (long long)(kt * 32 + k) * 1024 + n0 + ng;
    u16* dh = hi + zoff + ((long long)kt * 1024 + n0) * 32 + k;
    u16* dl = lo + zoff + ((long long)kt * 1024 + n0) * 32 + k;
#pragma unroll
    for (int t = 0; t < 4; t++) {
        const float4 v = *(const float4*)(src + t * 4);
        u16 h0, l0, h1, l1, h2, l2, h3, l3;
        split1(v.x, h0, l0); split1(v.y, h1, l1);
        split1(v.z, h2, l2); split1(v.w, h3, l3);
        const int nb = (ng + t * 4) * 32;
        dh[nb]      = h0; dl[nb]      = l0;
        dh[nb + 32] = h1; dl[nb + 32] = l1;
        dh[nb + 64] = h2; dl[nb + 64] = l2;
        dh[nb + 96] = h3; dl[nb + 96] = l3;
    }
}

// ===========================================================================
// GEMM (fast path): A from pre-split planes (A-tiled [kt][M][32]),
// B from weight planes ([kt][1024][32]).  C = act(A@W + bias).
// 128x128 tile, BK=32, 4 waves, 4x4 of 16x16x32 MFMA, 3 MFMAs per product.
// OUTP=1: write hi/lo planes (A-tiled, stride MC, row offset moff).
// OUTP=0: write fp32 row-major [*, 1024].
// ===========================================================================
template <int RELU, int OUTP>
__global__ __launch_bounds__(256) void gemm_fast(
    const u16* __restrict__ Ahp, const u16* __restrict__ Alp, int MA, int moff,
    const u16* __restrict__ Bhp, const u16* __restrict__ Blp,
    const float* __restrict__ bias,
    float* __restrict__ Cf,
    u16* __restrict__ Chp, u16* __restrict__ Clp, int MC,
    int K)
{
    __shared__ alignas(16) u16 Ah[4096], Al[4096], Bh[4096], Bl[4096];

    const int tid  = threadIdx.x;
    const int lane = tid & 63;
    const int wv   = tid >> 6;
    const int wm   = wv >> 1, wn = wv & 1;
    const int fr   = lane & 15;
    const int fq   = lane >> 4;
    const int m0   = blockIdx.y * 128;
    const int n0   = blockIdx.x * 128;
    const int o    = tid * 8;            // staging offset (shorts)

    f32x4 acc[4][4];
#pragma unroll
    for (int i = 0; i < 4; i++)
#pragma unroll
        for (int j = 0; j < 4; j++) acc[i][j] = 0;

    const int KT = K >> 5;
    for (int kt = 0; kt < KT; kt++) {
        const long long aoff = ((long long)kt * MA + moff + m0) * 32;
        const long long boff = ((long long)kt * 1024 + n0) * 32;
        const uint4 va0 = *(const uint4*)(Ahp + aoff + o);
        const uint4 va1 = *(const uint4*)(Ahp + aoff + o + 2048);
        const uint4 vb0 = *(const uint4*)(Alp + aoff + o);
        const uint4 vb1 = *(const uint4*)(Alp + aoff + o + 2048);
        const uint4 vc0 = *(const uint4*)(Bhp + boff + o);
        const uint4 vc1 = *(const uint4*)(Bhp + boff + o + 2048);
        const uint4 vd0 = *(const uint4*)(Blp + boff + o);
        const uint4 vd1 = *(const uint4*)(Blp + boff + o + 2048);
        *(uint4*)&Ah[o] = va0; *(uint4*)&Ah[o + 2048] = va1;
        *(uint4*)&Al[o] = vb0; *(uint4*)&Al[o + 2048] = vb1;
        *(uint4*)&Bh[o] = vc0; *(uint4*)&Bh[o + 2048] = vc1;
        *(uint4*)&Bl[o] = vd0; *(uint4*)&Bl[o + 2048] = vd1;
        __syncthreads();

        bf16x8 ah[4], al[4], bh[4], bl[4];
#pragma unroll
        for (int i = 0; i < 4; i++) {
            const int off = (wm * 64 + i * 16 + fr) * 32 + fq * 8;
            ah[i] = *(const bf16x8*)&Ah[off];
            al[i] = *(const bf16x8*)&Al[off];
        }
#pragma unroll
        for (int j = 0; j < 4; j++) {
            const int off = (wn * 64 + j * 16 + fr) * 32 + fq * 8;
            bh[j] = *(const bf16x8*)&Bh[off];
            bl[j] = *(const bf16x8*)&Bl[off];
        }
#pragma unroll
        for (int i = 0; i < 4; i++)
#pragma unroll
            for (int j = 0; j < 4; j++) {
                acc[i][j] = __builtin_amdgcn_mfma_f32_16x16x32_bf16(ah[i], bh[j], acc[i][j], 0, 0, 0);
                acc[i][j] = __builtin_amdgcn_mfma_f32_16x16x32_bf16(ah[i], bl[j], acc[i][j], 0, 0, 0);
                acc[i][j] = __builtin_amdgcn_mfma_f32_16x16x32_bf16(al[i], bh[j], acc[i][j], 0, 0, 0);
            }
        __syncthreads();
    }

#pragma unroll
    for (int j = 0; j < 4; j++) {
        const int n = n0 + wn * 64 + j * 16 + fr;
        const float bb = bias[n];
#pragma unroll
        for (int i = 0; i < 4; i++) {
#pragma unroll
            for (int r = 0; r < 4; r++) {
                const int m = m0 + wm * 64 + i * 16 + fq * 4 + r;
                float v = acc[i][j][r] + bb;
                if (RELU) v = fmaxf(v, 0.0f);
                if (OUTP) {
                    u16 h, l;
                    split1(v, h, l);
                    const long long d = ((long long)(n >> 5) * MC + moff + m) * 32 + (n & 31);
                    Chp[d] = h;
                    Clp[d] = l;
                } else {
                    Cf[(long long)m * 1024 + n] = v;
                }
            }
        }
    }
}

// ===========================================================================
// GEMM (convert path, for enc/dec): A fp32 with 2-region concat support,
// split in-kernel; B from weight planes.  Output: hi/lo planes.
// ===========================================================================
template <int RELU>
__global__ __launch_bounds__(256) void gemm_cvt(
    const float* __restrict__ src1, int lda1, int kofs1,
    const float* __restrict__ src2, int lda2, int ksplit,
    const u16* __restrict__ Bhp, const u16* __restrict__ Blp,
    const float* __restrict__ bias,
    u16* __restrict__ Chp, u16* __restrict__ Clp, int MC,
    int K)
{
    __shared__ alignas(16) u16 Ah[4096], Al[4096], Bh[4096], Bl[4096];

    const int tid  = threadIdx.x;
    const int lane = tid & 63;
    const int wv   = tid >> 6;
    const int wm   = wv >> 1, wn = wv & 1;
    const int fr   = lane & 15;
    const int fq   = lane >> 4;
    const int m0   = blockIdx.y * 128;
    const int n0   = blockIdx.x * 128;
    const int ar   = tid >> 3;          // 0..31
    const int akq  = tid & 7;           // 0..7

    f32x4 acc[4][4];
#pragma unroll
    for (int i = 0; i < 4; i++)
#pragma unroll
        for (int j = 0; j < 4; j++) acc[i][j] = 0;

    const int KT = K >> 5;
    for (int kt = 0; kt < KT; kt++) {
        const int k0 = kt * 32;
        const float* srcp; int ldk, kc;
        if (k0 < ksplit) { srcp = src1; ldk = lda1; kc = k0 + kofs1; }
        else             { srcp = src2; ldk = lda2; kc = k0 - ksplit; }

        // stage A: fp32 -> split -> LDS (conflict-free map)
#pragma unroll
        for (int it = 0; it < 4; it++) {
            const int row = ar + it * 32;
            const float4 v = *(const float4*)(srcp + (long long)(m0 + row) * ldk + kc + akq * 4);
            uint2 hi, lo;
            splitA4(v, hi, lo);
            *(uint2*)&Ah[row * 32 + akq * 4] = hi;
            *(uint2*)&Al[row * 32 + akq * 4] = lo;
        }
        // stage B from planes
        const long long boff = ((long long)kt * 1024 + n0) * 32;
#pragma unroll
        for (int it = 0; it < 4; it++) {
            const int row = ar + it * 32;
            const long long go = boff + (long long)row * 32 + akq * 4;
            *(uint2*)&Bh[row * 32 + akq * 4] = *(const uint2*)(Bhp + go);
            *(uint2*)&Bl[row * 32 + akq * 4] = *(const uint2*)(Blp + go);
        }
        __syncthreads();

        bf16x8 ah[4], al[4], bh[4], bl[4];
#pragma unroll
        for (int i = 0; i < 4; i++) {
            const int off = (wm * 64 + i * 16 + fr) * 32 + fq * 8;
            ah[i] = *(const bf16x8*)&Ah[off];
            al[i] = *(const bf16x8*)&Al[off];
        }
#pragma unroll
        for (int j = 0; j < 4; j++) {
            const int off = (wn * 64 + j * 16 + fr) * 32 + fq * 8;
            bh[j] = *(const bf16x8*)&Bh[off];
            bl[j] = *(const bf16x8*)&Bl[off];
        }
#pragma unroll
        for (int i = 0; i < 4; i++)
#pragma unroll
            for (int j = 0; j < 4; j++) {
                acc[i][j] = __builtin_amdgcn_mfma_f32_16x16x32_bf16(ah[i], bh[j], acc[i][j], 0, 0, 0);
                acc[i][j] = __builtin_amdgcn_mfma_f32_16x16x32_bf16(ah[i], bl[j], acc[i][j], 0, 0, 0);
                acc[i][j] = __builtin_amdgcn_mfma_f32_16x16x32_bf16(al[i], bh[j], acc[i][j], 0, 0, 0);
            }
        __syncthreads();
    }

#pragma unroll
    for (int j = 0; j < 4; j++) {
        const int n = n0 + wn * 64 + j * 16 + fr;
        const float bb = bias[n];
#pragma unroll
        for (int i = 0; i < 4; i++) {
#pragma unroll
            for (int r = 0; r < 4; r++) {
                const int m = m0 + wm * 64 + i * 16 + fq * 4 + r;
                float v = acc[i][j][r] + bb;
                if (RELU) v = fmaxf(v, 0.0f);
                u16 h, l;
                split1(v, h, l);
                const long long d = ((long long)(n >> 5) * MC + m) * 32 + (n & 31);
                Chp[d] = h;
                Clp[d] = l;
            }
        }
    }
}

// ===========================================================================
// Heads: per-head GEMM from planes; epilogue writes relu(head) fp16 +
// partial score dots vs decH (fp32).  Grid (8, BC/128, 8).
// ===========================================================================
__global__ __launch_bounds__(256) void heads_kernel(
    const u16* __restrict__ Ahp, const u16* __restrict__ Alp, int MA, int moff,
    const u16* __restrict__ Whp, const u16* __restrict__ Wlp,
    const float* __restrict__ b_heads,
    const float* __restrict__ decH,      // chunk-local [BC][1024]
    __half* __restrict__ headsb,         // [BC][8][1024]
    float* __restrict__ scoresp)         // [64][BC]
{
    __shared__ alignas(16) u16 Ah[4096], Al[4096], Bh[4096], Bl[4096];
    __shared__ float scred[2][128];

    const int h = blockIdx.z;
    const u16* Bhp = Whp + (long long)h * 1024 * 1024;
    const u16* Blp = Wlp + (long long)h * 1024 * 1024;
    const float* bias = b_heads + h * 1024;

    const int tid  = threadIdx.x;
    const int lane = tid & 63;
    const int wv   = tid >> 6;
    const int wm   = wv >> 1, wn = wv & 1;
    const int fr   = lane & 15;
    const int fq   = lane >> 4;
    const int m0   = blockIdx.y * 128;
    const int n0   = blockIdx.x * 128;
    const int o    = tid * 8;

    f32x4 acc[4][4];
#pragma unroll
    for (int i = 0; i < 4; i++)
#pragma unroll
        for (int j = 0; j < 4; j++) acc[i][j] = 0;

    for (int kt = 0; kt < 32; kt++) {
        const long long aoff = ((long long)kt * MA + moff + m0) * 32;
        const long long boff = ((long long)kt * 1024 + n0) * 32;
        const uint4 va0 = *(const uint4*)(Ahp + aoff + o);
        const uint4 va1 = *(const uint4*)(Ahp + aoff + o + 2048);
        const uint4 vb0 = *(const uint4*)(Alp + aoff + o);
        const uint4 vb1 = *(const uint4*)(Alp + aoff + o + 2048);
        const uint4 vc0 = *(const uint4*)(Bhp + boff + o);
        const uint4 vc1 = *(const uint4*)(Bhp + boff + o + 2048);
        const uint4 vd0 = *(const uint4*)(Blp + boff + o);
        const uint4 vd1 = *(const uint4*)(Blp + boff + o + 2048);
        *(uint4*)&Ah[o] = va0; *(uint4*)&Ah[o + 2048] = va1;
        *(uint4*)&Al[o] = vb0; *(uint4*)&Al[o + 2048] = vb1;
        *(uint4*)&Bh[o] = vc0; *(uint4*)&Bh[o + 2048] = vc1;
        *(uint4*)&Bl[o] = vd0; *(uint4*)&Bl[o + 2048] = vd1;
        __syncthreads();

        bf16x8 ah[4], al[4], bh[4], bl[4];
#pragma unroll
        for (int i = 0; i < 4; i++) {
            const int off = (wm * 64 + i * 16 + fr) * 32 + fq * 8;
            ah[i] = *(const bf16x8*)&Ah[off];
            al[i] = *(const bf16x8*)&Al[off];
        }
#pragma unroll
        for (int j = 0; j < 4; j++) {
            const int off = (wn * 64 + j * 16 + fr) * 32 + fq * 8;
            bh[j] = *(const bf16x8*)&Bh[off];
            bl[j] = *(const bf16x8*)&Bl[off];
        }
#pragma unroll
        for (int i = 0; i < 4; i++)
#pragma unroll
            for (int j = 0; j < 4; j++) {
                acc[i][j] = __builtin_amdgcn_mfma_f32_16x16x32_bf16(ah[i], bh[j], acc[i][j], 0, 0, 0);
                acc[i][j] = __builtin_amdgcn_mfma_f32_16x16x32_bf16(ah[i], bl[j], acc[i][j], 0, 0, 0);
                acc[i][j] = __builtin_amdgcn_mfma_f32_16x16x32_bf16(al[i], bh[j], acc[i][j], 0, 0, 0);
            }
        __syncthreads();
    }

    // epilogue: relu -> fp16 headsb, partial score vs decH
    float part[4][4];
#pragma unroll
    for (int i = 0; i < 4; i++)
#pragma unroll
        for (int r = 0; r < 4; r++) part[i][r] = 0.0f;

#pragma unroll
    for (int j = 0; j < 4; j++) {
        const int n = n0 + wn * 64 + j * 16 + fr;
        const float bb = bias[n];
#pragma unroll
        for (int i = 0; i < 4; i++) {
#pragma unroll
            for (int r = 0; r < 4; r++) {
                const int b_loc = m0 + wm * 64 + i * 16 + fq * 4 + r;
                const float v = fmaxf(acc[i][j][r] + bb, 0.0f);
                headsb[((long long)b_loc * HEADS + h) * 1024 + n] = __float2half(v);
                part[i][r] = fmaf(v, decH[(long long)b_loc * 1024 + n], part[i][r]);
            }
        }
    }
#pragma unroll
    for (int off = 1; off < 16; off <<= 1)
#pragma unroll
        for (int i = 0; i < 4; i++)
#pragma unroll
            for (int r = 0; r < 4; r++)
                part[i][r] += __shfl_xor(part[i][r], off, 64);

    if (fr == 0) {
#pragma unroll
        for (int i = 0; i < 4; i++)
#pragma unroll
            for (int r = 0; r < 4; r++)
                scred[wn][wm * 64 + i * 16 + fq * 4 + r] = part[i][r];
    }
    __syncthreads();
    if (tid < 128) {
        const float sv = scred[0][tid] + scred[1][tid];
        scoresp[(long long)(h * 8 + blockIdx.x) * BC + m0 + tid] = sv;
    }
}

// ---------------------------------------------------------------------------
// softmax over heads (per chunk)
// ---------------------------------------------------------------------------
__global__ __launch_bounds__(256) void softmax_kernel(
    const float* __restrict__ scoresp, float* __restrict__ attn)
{
    const int b = blockIdx.x * 256 + threadIdx.x;   // 0..BC-1
    float sc[HEADS];
#pragma unroll
    for (int h = 0; h < HEADS; h++) {
        float s = 0.0f;
#pragma unroll
        for (int nt = 0; nt < 8; nt++)
            s += scoresp[(long long)(h * 8 + nt) * BC + b];
        sc[h] = s;
    }
    float mx = sc[0];
#pragma unroll
    for (int h = 1; h < HEADS; h++) mx = fmaxf(mx, sc[h]);
    float e[HEADS], sum = 0.0f;
#pragma unroll
    for (int h = 0; h < HEADS; h++) { e[h] = __expf(sc[h] - mx); sum += e[h]; }
    const float inv = 1.0f / sum;
#pragma unroll
    for (int h = 0; h < HEADS; h++) attn[(long long)b * HEADS + h] = e[h] * inv;
}

// ---------------------------------------------------------------------------
// context: ctx[b][d] = sum_h attn[b][h]*heads[b][h][d]; writes hi/lo planes
// (A-tiled, stride MC, rows row0+b).  One block per local row b.
// ---------------------------------------------------------------------------
__global__ __launch_bounds__(256) void context_kernel(
    const __half* __restrict__ headsb, const float* __restrict__ attn,
    u16* __restrict__ ctx_hi, u16* __restrict__ ctx_lo, int MC, int row0)
{
    const int b = blockIdx.x;
    const int d = threadIdx.x * 4;
    float w[HEADS];
#pragma unroll
    for (int h = 0; h < HEADS; h++) w[h] = attn[(long long)b * HEADS + h];
    float4 acc = make_float4(0.f, 0.f, 0.f, 0.f);
#pragma unroll
    for (int h = 0; h < HEADS; h++) {
        const __half2* hp = (const __half2*)(headsb + ((long long)b * HEADS + h) * 1024 + d);
        const float2 f0 = __half22float2(hp[0]);
        const float2 f1 = __half22float2(hp[1]);
        acc.x = fmaf(w[h], f0.x, acc.x);
        acc.y = fmaf(w[h], f0.y, acc.y);
        acc.z = fmaf(w[h], f1.x, acc.z);
        acc.w = fmaf(w[h], f1.y, acc.w);
    }
    uint2 hi, lo;
    splitA4(acc, hi, lo);
    const long long off = ((long long)(d >> 5) * MC + row0 + b) * 32 + (d & 31);
    *(uint2*)(ctx_hi + off) = hi;
    *(uint2*)(ctx_lo + off) = lo;
}

// ---------------------------------------------------------------------------
// fc2: q[b] = sum_d x[b,d]*W2[d] + b2[0]
// ---------------------------------------------------------------------------
__global__ __launch_bounds__(256) void fc2_kernel(
    const float* __restrict__ x, const float* __restrict__ W2,
    const float* __restrict__ b2, float* __restrict__ q)
{
    const int b   = blockIdx.x;
    const int tid = threadIdx.x;
    __shared__ float red[4];

    const float4 xv = *(const float4*)(x + (long long)b * 1024 + tid * 4);
    const float4 wv = *(const float4*)(W2 + tid * 4);
    float p = xv.x * wv.x + xv.y * wv.y + xv.z * wv.z + xv.w * wv.w;
#pragma unroll
    for (int off = 32; off > 0; off >>= 1) p += __shfl_down(p, off, 64);
    if ((tid & 63) == 0) red[tid >> 6] = p;
    __syncthreads();
    if (tid == 0) q[b] = red[0] + red[1] + red[2] + red[3] + b2[0];
}

// ---------------------------------------------------------------------------
extern "C" void kernel_launch(void* const* d_in, const int* in_sizes, int n_in,
                              void* d_out, int out_size, void* d_ws, size_t ws_size,
                              hipStream_t stream)
{
    const float* s        = (const float*)d_in[0];
    const float* a        = (const float*)d_in[1];
    const float* W_enc_in = (const float*)d_in[2];
    const float* b_enc_in = (const float*)d_in[3];
    const float* W_dec_in = (const float*)d_in[4];
    const float* b_dec_in = (const float*)d_in[5];
    const float* W_eh     = (const float*)d_in[6];
    const float* b_eh     = (const float*)d_in[7];
    const float* W_heads  = (const float*)d_in[8];
    const float* b_heads  = (const float*)d_in[9];
    const float* W_dh     = (const float*)d_in[10];
    const float* b_dh     = (const float*)d_in[11];
    const float* W1       = (const float*)d_in[12];
    const float* b1       = (const float*)d_in[13];
    const float* W2       = (const float*)d_in[14];
    const float* b2       = (const float*)d_in[15];
    float* q_out = (float*)d_out;

    // ---- weight plane layout (shorts) -------------------------------------
    u16* P = (u16*)d_ws;
    u16* enc_hi = P; P += 557056;      // 544*1024
    u16* enc_lo = P; P += 557056;
    u16* dec_hi = P; P += 98304;       // 96*1024
    u16* dec_lo = P; P += 98304;
    u16* eh_hi  = P; P += 1048576;
    u16* eh_lo  = P; P += 1048576;
    u16* dh_hi  = P; P += 1048576;
    u16* dh_lo  = P; P += 1048576;
    u16* w1_hi  = P; P += 1048576;
    u16* w1_lo  = P; P += 1048576;
    u16* wh_hi  = P; P += 8388608;     // 8*1024*1024
    u16* wh_lo  = P; P += 8388608;
    char* act = (char*)P;              // 48,758,784 bytes consumed

    const dim3 blk(256);

    // ---- weight conversions (both modes) ----------------------------------
    split_weight_kernel<<<dim3(17, 8, 1), blk, 0, stream>>>(W_enc_in, enc_hi, enc_lo, 544);
    split_weight_kernel<<<dim3(3, 8, 1), blk, 0, stream>>>(W_dec_in, dec_hi, dec_lo, 96);
    split_weight_kernel<<<dim3(32, 8, 1), blk, 0, stream>>>(W_eh, eh_hi, eh_lo, 1024);
    split_weight_kernel<<<dim3(32, 8, 1), blk, 0, stream>>>(W_dh, dh_hi, dh_lo, 1024);
    split_weight_kernel<<<dim3(32, 8, 1), blk, 0, stream>>>(W1, w1_hi, w1_lo, 1024);
    split_weight_kernel<<<dim3(32, 8, 8), blk, 0, stream>>>(W_heads, wh_hi, wh_lo, 1024);

    const bool high = (ws_size >= 150011904ULL);

    if (high) {
        // [bufA_hi|bufA_lo (33.55MB, headsb overlays)] [encH planes 33.55MB]
        // [decH fp32 33.55MB] [scoresp 512KB] [attn 64KB]
        u16*    bufA_hi = (u16*)act;
        u16*    bufA_lo = bufA_hi + 8388608;
        __half* headsb  = (__half*)act;
        u16*    encH_hi = (u16*)(act + 33554432);
        u16*    encH_lo = encH_hi + 8388608;
        float*  decH    = (float*)(act + 2LL * 33554432);
        float*  scoresp = (float*)(act + 3LL * 33554432);
        float*  attnb   = scoresp + 64LL * BC;

        const dim3 gg(8, 64, 1);
        // enc_input = [s|a[:, :32]] @ W_enc + b        -> bufA planes
        gemm_cvt<0><<<gg, blk, 0, stream>>>(s, 512, 0, a, 128, 512,
            enc_hi, enc_lo, b_enc_in, bufA_hi, bufA_lo, 8192, 544);
        // encoder_h = relu(enc_input @ W_eh + b_eh)    -> encH planes
        gemm_fast<1, 1><<<gg, blk, 0, stream>>>(bufA_hi, bufA_lo, 8192, 0,
            eh_hi, eh_lo, b_eh, nullptr, encH_hi, encH_lo, 8192, 1024);
        // dec_input = a[:,32:] @ W_dec + b             -> bufA planes
        gemm_cvt<0><<<gg, blk, 0, stream>>>(a, 128, 32, a, 128, 1 << 28,
            dec_hi, dec_lo, b_dec_in, bufA_hi, bufA_lo, 8192, 96);
        // decoder_H = relu(dec_input @ W_dh + b_dh)    -> decH fp32
        gemm_fast<1, 0><<<gg, blk, 0, stream>>>(bufA_hi, bufA_lo, 8192, 0,
            dh_hi, dh_lo, b_dh, decH, nullptr, nullptr, 0, 1024);

        for (int c = 0; c < BATCH / BC; c++) {
            heads_kernel<<<dim3(8, BC / 128, 8), blk, 0, stream>>>(
                encH_hi, encH_lo, 8192, c * BC, wh_hi, wh_lo, b_heads,
                decH + (long long)c * BC * 1024, headsb, scoresp);
            softmax_kernel<<<dim3(BC / 256), blk, 0, stream>>>(scoresp, attnb);
            context_kernel<<<dim3(BC), blk, 0, stream>>>(
                headsb, attnb, encH_hi, encH_lo, 8192, c * BC);
        }
        // x = relu(ctx @ W1 + b1) -> decH (dead)
        gemm_fast<1, 0><<<gg, blk, 0, stream>>>(encH_hi, encH_lo, 8192, 0,
            w1_hi, w1_lo, b1, decH, nullptr, nullptr, 0, 1024);
        fc2_kernel<<<dim3(BATCH), blk, 0, stream>>>(decH, W2, b2, q_out);
    } else {
        // low-memory: fully chunked.  [headsb 33.55MB (bufA overlays)]
        // [encH planes 8.39MB] [decH fp32 8.39MB] [scoresp] [attn]
        __half* headsb  = (__half*)act;
        u16*    bufA_hi = (u16*)act;
        u16*    bufA_lo = bufA_hi + 2097152;
        u16*    encH_hi = (u16*)(act + 33554432);
        u16*    encH_lo = encH_hi + 2097152;
        float*  decH    = (float*)(act + 33554432 + 8388608);
        float*  scoresp = (float*)(act + 33554432 + 2LL * 8388608);
        float*  attnb   = scoresp + 64LL * BC;

        const dim3 gg(8, BC / 128, 1);
        for (int c = 0; c < BATCH / BC; c++) {
            const float* sC = s + (long long)c * BC * 512;
            const float* aC = a + (long long)c * BC * 128;
            gemm_cvt<0><<<gg, blk, 0, stream>>>(sC, 512, 0, aC, 128, 512,
                enc_hi, enc_lo, b_enc_in, bufA_hi, bufA_lo, BC, 544);
            gemm_fast<1, 1><<<gg, blk, 0, stream>>>(bufA_hi, bufA_lo, BC, 0,
                eh_hi, eh_lo, b_eh, nullptr, encH_hi, encH_lo, BC, 1024);
            gemm_cvt<0><<<gg, blk, 0, stream>>>(aC, 128, 32, aC, 128, 1 << 28,
                dec_hi, dec_lo, b_dec_in, bufA_hi, bufA_lo, BC, 96);
            gemm_fast<1, 0><<<gg, blk, 0, stream>>>(bufA_hi, bufA_lo, BC, 0,
                dh_hi, dh_lo, b_dh, decH, nullptr, nullptr, 0, 1024);
            heads_kernel<<<dim3(8, BC / 128, 8), blk, 0, stream>>>(
                encH_hi, encH_lo, BC, 0, wh_hi, wh_lo, b_heads,
                decH, headsb, scoresp);
            softmax_kernel<<<dim3(BC / 256), blk, 0, stream>>>(scoresp, attnb);
            context_kernel<<<dim3(BC), blk, 0, stream>>>(
                headsb, attnb, encH_hi, encH_lo, BC, 0);
            gemm_fast<1, 0><<<gg, blk, 0, stream>>>(encH_hi, encH_lo, BC, 0,
                w1_hi, w1_lo, b1, decH, nullptr, nullptr, 0, 1024);
            fc2_kernel<<<dim3(BC), blk, 0, stream>>>(decH, W2, b2, q_out + (long long)c * BC);
        }
    }
}

// Round 5
// 828.270 us; speedup vs baseline: 4.8965x; 1.0480x over previous
//
#include <hip/hip_runtime.h>
#include <hip/hip_bf16.h>
#include <hip/hip_fp16.h>

#define BATCH   8192
#define HID     1024
#define HEADS   8
#define BC      2048

typedef unsigned int  u32;
typedef unsigned short u16;
typedef __attribute__((ext_vector_type(8))) short bf16x8;
typedef __attribute__((ext_vector_type(4))) float f32x4;

// ---------------------------------------------------------------------------
// hi/lo split helpers (truncation both; x = hi + lo + O(2^-16 |x|))
// ---------------------------------------------------------------------------
__device__ __forceinline__ u32 pack_hi2(u32 u0, u32 u1) {
    return (u0 >> 16) | (u1 & 0xFFFF0000u);
}
__device__ __forceinline__ void split1(float x, u16& h, u16& l) {
    const u32 u = __float_as_uint(x);
    h = (u16)(u >> 16);
    const float r = x - __uint_as_float(u & 0xFFFF0000u);
    l = (u16)(__float_as_uint(r) >> 16);
}
__device__ __forceinline__ void splitA4(float4 v, uint2& hi, uint2& lo) {
    u32 u0 = __float_as_uint(v.x), u1 = __float_as_uint(v.y),
        u2 = __float_as_uint(v.z), u3 = __float_as_uint(v.w);
    float r0 = v.x - __uint_as_float(u0 & 0xFFFF0000u);
    float r1 = v.y - __uint_as_float(u1 & 0xFFFF0000u);
    float r2 = v.z - __uint_as_float(u2 & 0xFFFF0000u);
    float r3 = v.w - __uint_as_float(u3 & 0xFFFF0000u);
    hi.x = pack_hi2(u0, u1);
    hi.y = pack_hi2(u2, u3);
    lo.x = pack_hi2(__float_as_uint(r0), __float_as_uint(r1));
    lo.y = pack_hi2(__float_as_uint(r2), __float_as_uint(r3));
}

// async global->LDS, 16 B per lane; lds base must be wave-uniform
__device__ __forceinline__ void gld16(const u16* g, u16* l) {
    __builtin_amdgcn_global_load_lds(
        (const __attribute__((address_space(1))) u32*)g,
        (__attribute__((address_space(3))) u32*)l, 16, 0, 0);
}

// ---------------------------------------------------------------------------
// Weight conversion: W fp32 [K][1024] (z-batched) -> hi/lo bf16 planes in
// k-tiled transposed layout  Wt[kt][n][32]  (kt = k/32).
// ---------------------------------------------------------------------------
__global__ __launch_bounds__(256) void split_weight_kernel(
    const float* __restrict__ W, u16* __restrict__ hi, u16* __restrict__ lo,
    int K)
{
    const long long zoff = (long long)blockIdx.z * K * 1024;
    const int kt  = blockIdx.x;
    const int n0  = blockIdx.y * 128;
    const int tid = threadIdx.x;
    const int k   = tid >> 3;            // 0..31
    const int ng  = (tid & 7) * 16;      // 0,16,...,112
    const float* src = W + zoff + (long long)(kt * 32 + k) * 1024 + n0 + ng;
    u16* dh = hi + zoff + ((long long)kt * 1024 + n0) * 32 + k;
    u16* dl = lo + zoff + ((long long)kt * 1024 + n0) * 32 + k;
#pragma unroll
    for (int t = 0; t < 4; t++) {
        const float4 v = *(const float4*)(src + t * 4);
        u16 h0, l0, h1, l1, h2, l2, h3, l3;
        split1(v.x, h0, l0); split1(v.y, h1, l1);
        split1(v.z, h2, l2); split1(v.w, h3, l3);
        const int nb = (ng + t * 4) * 32;
        dh[nb]      = h0; dl[nb]      = l0;
        dh[nb + 32] = h1; dl[nb + 32] = l1;
        dh[nb + 64] = h2; dl[nb + 64] = l2;
        dh[nb + 96] = h3; dl[nb + 96] = l3;
    }
}

// Common per-thread geometry for the MFMA kernels.
// Fragment-read swizzle: logical (row, kgroup fq) lives at slot fq^(row&3);
// row&3 == fr&3 and the async-copy source carries the matching permutation,
// so both sides are lane-constant.
#define MFMA_GEOM \
    const int tid  = threadIdx.x; \
    const int lane = tid & 63; \
    const int wv   = tid >> 6; \
    const int wm   = wv >> 1, wn = wv & 1; \
    const int fr   = lane & 15; \
    const int fq   = lane >> 4; \
    const int fqx  = (fq ^ (fr & 3)) * 8; \
    const int lro  = (lane >> 2) * 32 + (((lane & 3) ^ ((lane >> 2) & 3)) * 8); \
    const int br0  = wv * 16; \
    const int br1  = 64 + wv * 16;

// ===========================================================================
// GEMM (fast path): A,B from pre-split planes; async LDS staging.
// 128x128 tile, BK=32, 4 waves, 4x4 of 16x16x32 MFMA, 3 MFMAs per product.
// OUTP=1: write hi/lo planes (A-tiled, stride MC, row offset moff).
// OUTP=0: write fp32 row-major [*, 1024].
// ===========================================================================
template <int RELU, int OUTP>
__global__ __launch_bounds__(256) void gemm_fast(
    const u16* __restrict__ Ahp, const u16* __restrict__ Alp, int MA, int moff,
    const u16* __restrict__ Bhp, const u16* __restrict__ Blp,
    const float* __restrict__ bias,
    float* __restrict__ Cf,
    u16* __restrict__ Chp, u16* __restrict__ Clp, int MC,
    int K)
{
    __shared__ alignas(16) u16 Ah[4096], Al[4096], Bh[4096], Bl[4096];
    MFMA_GEOM
    const int m0 = blockIdx.y * 128;
    const int n0 = blockIdx.x * 128;

    f32x4 acc[4][4];
#pragma unroll
    for (int i = 0; i < 4; i++)
#pragma unroll
        for (int j = 0; j < 4; j++) acc[i][j] = 0;

    const int KT = K >> 5;
    for (int kt = 0; kt < KT; kt++) {
        const u16* Ag  = Ahp + ((long long)kt * MA + moff + m0) * 32;
        const u16* Ag2 = Alp + ((long long)kt * MA + moff + m0) * 32;
        const u16* Bg  = Bhp + ((long long)kt * 1024 + n0) * 32;
        const u16* Bg2 = Blp + ((long long)kt * 1024 + n0) * 32;
        gld16(Ag  + br0 * 32 + lro, &Ah[br0 * 32]);
        gld16(Ag  + br1 * 32 + lro, &Ah[br1 * 32]);
        gld16(Ag2 + br0 * 32 + lro, &Al[br0 * 32]);
        gld16(Ag2 + br1 * 32 + lro, &Al[br1 * 32]);
        gld16(Bg  + br0 * 32 + lro, &Bh[br0 * 32]);
        gld16(Bg  + br1 * 32 + lro, &Bh[br1 * 32]);
        gld16(Bg2 + br0 * 32 + lro, &Bl[br0 * 32]);
        gld16(Bg2 + br1 * 32 + lro, &Bl[br1 * 32]);
        __syncthreads();

        bf16x8 ah[4], al[4], bh[4], bl[4];
#pragma unroll
        for (int i = 0; i < 4; i++) {
            const int off = (wm * 64 + i * 16 + fr) * 32 + fqx;
            ah[i] = *(const bf16x8*)&Ah[off];
            al[i] = *(const bf16x8*)&Al[off];
        }
#pragma unroll
        for (int j = 0; j < 4; j++) {
            const int off = (wn * 64 + j * 16 + fr) * 32 + fqx;
            bh[j] = *(const bf16x8*)&Bh[off];
            bl[j] = *(const bf16x8*)&Bl[off];
        }
#pragma unroll
        for (int i = 0; i < 4; i++)
#pragma unroll
            for (int j = 0; j < 4; j++) {
                acc[i][j] = __builtin_amdgcn_mfma_f32_16x16x32_bf16(ah[i], bh[j], acc[i][j], 0, 0, 0);
                acc[i][j] = __builtin_amdgcn_mfma_f32_16x16x32_bf16(ah[i], bl[j], acc[i][j], 0, 0, 0);
                acc[i][j] = __builtin_amdgcn_mfma_f32_16x16x32_bf16(al[i], bh[j], acc[i][j], 0, 0, 0);
            }
        __syncthreads();
    }

#pragma unroll
    for (int j = 0; j < 4; j++) {
        const int n = n0 + wn * 64 + j * 16 + fr;
        const float bb = bias[n];
#pragma unroll
        for (int i = 0; i < 4; i++) {
#pragma unroll
            for (int r = 0; r < 4; r++) {
                const int m = m0 + wm * 64 + i * 16 + fq * 4 + r;
                float v = acc[i][j][r] + bb;
                if (RELU) v = fmaxf(v, 0.0f);
                if (OUTP) {
                    u16 h, l;
                    split1(v, h, l);
                    const long long d = ((long long)(n >> 5) * MC + moff + m) * 32 + (n & 31);
                    Chp[d] = h;
                    Clp[d] = l;
                } else {
                    Cf[(long long)m * 1024 + n] = v;
                }
            }
        }
    }
}

// ===========================================================================
// GEMM (convert path, enc/dec): A fp32 (2-region concat), split in-kernel
// with swizzled LDS writes; B async from planes.  Output: hi/lo planes.
// ===========================================================================
template <int RELU>
__global__ __launch_bounds__(256) void gemm_cvt(
    const float* __restrict__ src1, int lda1, int kofs1,
    const float* __restrict__ src2, int lda2, int ksplit,
    const u16* __restrict__ Bhp, const u16* __restrict__ Blp,
    const float* __restrict__ bias,
    u16* __restrict__ Chp, u16* __restrict__ Clp, int MC,
    int K)
{
    __shared__ alignas(16) u16 Ah[4096], Al[4096], Bh[4096], Bl[4096];
    MFMA_GEOM
    const int m0  = blockIdx.y * 128;
    const int n0  = blockIdx.x * 128;
    const int ar  = tid >> 3;            // 0..31
    const int akq = tid & 7;             // float4 group 0..7
    // swizzled A-write offset: slot s = akq>>1, within-slot half = akq&1
    const int awoff = (( (akq >> 1) ^ (ar & 3) ) * 8) + (akq & 1) * 4;

    f32x4 acc[4][4];
#pragma unroll
    for (int i = 0; i < 4; i++)
#pragma unroll
        for (int j = 0; j < 4; j++) acc[i][j] = 0;

    const int KT = K >> 5;
    for (int kt = 0; kt < KT; kt++) {
        const int k0 = kt * 32;
        const float* srcp; int ldk, kc;
        if (k0 < ksplit) { srcp = src1; ldk = lda1; kc = k0 + kofs1; }
        else             { srcp = src2; ldk = lda2; kc = k0 - ksplit; }

        // B async
        const u16* Bg  = Bhp + ((long long)kt * 1024 + n0) * 32;
        const u16* Bg2 = Blp + ((long long)kt * 1024 + n0) * 32;
        gld16(Bg  + br0 * 32 + lro, &Bh[br0 * 32]);
        gld16(Bg  + br1 * 32 + lro, &Bh[br1 * 32]);
        gld16(Bg2 + br0 * 32 + lro, &Bl[br0 * 32]);
        gld16(Bg2 + br1 * 32 + lro, &Bl[br1 * 32]);

        // A: fp32 -> split -> swizzled LDS write
#pragma unroll
        for (int it = 0; it < 4; it++) {
            const int row = ar + it * 32;
            const float4 v = *(const float4*)(srcp + (long long)(m0 + row) * ldk + kc + akq * 4);
            uint2 hi, lo;
            splitA4(v, hi, lo);
            *(uint2*)&Ah[row * 32 + awoff] = hi;
            *(uint2*)&Al[row * 32 + awoff] = lo;
        }
        __syncthreads();

        bf16x8 ah[4], al[4], bh[4], bl[4];
#pragma unroll
        for (int i = 0; i < 4; i++) {
            const int off = (wm * 64 + i * 16 + fr) * 32 + fqx;
            ah[i] = *(const bf16x8*)&Ah[off];
            al[i] = *(const bf16x8*)&Al[off];
        }
#pragma unroll
        for (int j = 0; j < 4; j++) {
            const int off = (wn * 64 + j * 16 + fr) * 32 + fqx;
            bh[j] = *(const bf16x8*)&Bh[off];
            bl[j] = *(const bf16x8*)&Bl[off];
        }
#pragma unroll
        for (int i = 0; i < 4; i++)
#pragma unroll
            for (int j = 0; j < 4; j++) {
                acc[i][j] = __builtin_amdgcn_mfma_f32_16x16x32_bf16(ah[i], bh[j], acc[i][j], 0, 0, 0);
                acc[i][j] = __builtin_amdgcn_mfma_f32_16x16x32_bf16(ah[i], bl[j], acc[i][j], 0, 0, 0);
                acc[i][j] = __builtin_amdgcn_mfma_f32_16x16x32_bf16(al[i], bh[j], acc[i][j], 0, 0, 0);
            }
        __syncthreads();
    }

#pragma unroll
    for (int j = 0; j < 4; j++) {
        const int n = n0 + wn * 64 + j * 16 + fr;
        const float bb = bias[n];
#pragma unroll
        for (int i = 0; i < 4; i++) {
#pragma unroll
            for (int r = 0; r < 4; r++) {
                const int m = m0 + wm * 64 + i * 16 + fq * 4 + r;
                float v = acc[i][j][r] + bb;
                if (RELU) v = fmaxf(v, 0.0f);
                u16 h, l;
                split1(v, h, l);
                const long long d = ((long long)(n >> 5) * MC + m) * 32 + (n & 31);
                Chp[d] = h;
                Clp[d] = l;
            }
        }
    }
}

// ===========================================================================
// Heads: per-head GEMM from planes (async staging); epilogue writes
// relu(head) fp16 + partial score dots vs decH.  Grid (8, BC/128, 8).
// ===========================================================================
__global__ __launch_bounds__(256) void heads_kernel(
    const u16* __restrict__ Ahp, const u16* __restrict__ Alp, int MA, int moff,
    const u16* __restrict__ Whp, const u16* __restrict__ Wlp,
    const float* __restrict__ b_heads,
    const float* __restrict__ decH,      // chunk-local [BC][1024]
    __half* __restrict__ headsb,         // [BC][8][1024]
    float* __restrict__ scoresp)         // [64][BC]
{
    __shared__ alignas(16) u16 Ah[4096], Al[4096], Bh[4096], Bl[4096];
    __shared__ float scred[2][128];
    MFMA_GEOM
    const int h = blockIdx.z;
    const u16* Bhp = Whp + (long long)h * 1024 * 1024;
    const u16* Blp = Wlp + (long long)h * 1024 * 1024;
    const float* bias = b_heads + h * 1024;
    const int m0 = blockIdx.y * 128;
    const int n0 = blockIdx.x * 128;

    f32x4 acc[4][4];
#pragma unroll
    for (int i = 0; i < 4; i++)
#pragma unroll
        for (int j = 0; j < 4; j++) acc[i][j] = 0;

    for (int kt = 0; kt < 32; kt++) {
        const u16* Ag  = Ahp + ((long long)kt * MA + moff + m0) * 32;
        const u16* Ag2 = Alp + ((long long)kt * MA + moff + m0) * 32;
        const u16* Bg  = Bhp + ((long long)kt * 1024 + n0) * 32;
        const u16* Bg2 = Blp + ((long long)kt * 1024 + n0) * 32;
        gld16(Ag  + br0 * 32 + lro, &Ah[br0 * 32]);
        gld16(Ag  + br1 * 32 + lro, &Ah[br1 * 32]);
        gld16(Ag2 + br0 * 32 + lro, &Al[br0 * 32]);
        gld16(Ag2 + br1 * 32 + lro, &Al[br1 * 32]);
        gld16(Bg  + br0 * 32 + lro, &Bh[br0 * 32]);
        gld16(Bg  + br1 * 32 + lro, &Bh[br1 * 32]);
        gld16(Bg2 + br0 * 32 + lro, &Bl[br0 * 32]);
        gld16(Bg2 + br1 * 32 + lro, &Bl[br1 * 32]);
        __syncthreads();

        bf16x8 ah[4], al[4], bh[4], bl[4];
#pragma unroll
        for (int i = 0; i < 4; i++) {
            const int off = (wm * 64 + i * 16 + fr) * 32 + fqx;
            ah[i] = *(const bf16x8*)&Ah[off];
            al[i] = *(const bf16x8*)&Al[off];
        }
#pragma unroll
        for (int j = 0; j < 4; j++) {
            const int off = (wn * 64 + j * 16 + fr) * 32 + fqx;
            bh[j] = *(const bf16x8*)&Bh[off];
            bl[j] = *(const bf16x8*)&Bl[off];
        }
#pragma unroll
        for (int i = 0; i < 4; i++)
#pragma unroll
            for (int j = 0; j < 4; j++) {
                acc[i][j] = __builtin_amdgcn_mfma_f32_16x16x32_bf16(ah[i], bh[j], acc[i][j], 0, 0, 0);
                acc[i][j] = __builtin_amdgcn_mfma_f32_16x16x32_bf16(ah[i], bl[j], acc[i][j], 0, 0, 0);
                acc[i][j] = __builtin_amdgcn_mfma_f32_16x16x32_bf16(al[i], bh[j], acc[i][j], 0, 0, 0);
            }
        __syncthreads();
    }

    // epilogue: relu -> fp16 headsb, partial score vs decH
    float part[4][4];
#pragma unroll
    for (int i = 0; i < 4; i++)
#pragma unroll
        for (int r = 0; r < 4; r++) part[i][r] = 0.0f;

#pragma unroll
    for (int j = 0; j < 4; j++) {
        const int n = n0 + wn * 64 + j * 16 + fr;
        const float bb = bias[n];
#pragma unroll
        for (int i = 0; i < 4; i++) {
#pragma unroll
            for (int r = 0; r < 4; r++) {
                const int b_loc = m0 + wm * 64 + i * 16 + fq * 4 + r;
                const float v = fmaxf(acc[i][j][r] + bb, 0.0f);
                headsb[((long long)b_loc * HEADS + h) * 1024 + n] = __float2half(v);
                part[i][r] = fmaf(v, decH[(long long)b_loc * 1024 + n], part[i][r]);
            }
        }
    }
#pragma unroll
    for (int off = 1; off < 16; off <<= 1)
#pragma unroll
        for (int i = 0; i < 4; i++)
#pragma unroll
            for (int r = 0; r < 4; r++)
                part[i][r] += __shfl_xor(part[i][r], off, 64);

    if (fr == 0) {
#pragma unroll
        for (int i = 0; i < 4; i++)
#pragma unroll
            for (int r = 0; r < 4; r++)
                scred[wn][wm * 64 + i * 16 + fq * 4 + r] = part[i][r];
    }
    __syncthreads();
    if (tid < 128) {
        const float sv = scred[0][tid] + scred[1][tid];
        scoresp[(long long)(h * 8 + blockIdx.x) * BC + m0 + tid] = sv;
    }
}

// ---------------------------------------------------------------------------
// softmax over heads (per chunk)
// ---------------------------------------------------------------------------
__global__ __launch_bounds__(256) void softmax_kernel(
    const float* __restrict__ scoresp, float* __restrict__ attn)
{
    const int b = blockIdx.x * 256 + threadIdx.x;   // 0..BC-1
    float sc[HEADS];
#pragma unroll
    for (int h = 0; h < HEADS; h++) {
        float s = 0.0f;
#pragma unroll
        for (int nt = 0; nt < 8; nt++)
            s += scoresp[(long long)(h * 8 + nt) * BC + b];
        sc[h] = s;
    }
    float mx = sc[0];
#pragma unroll
    for (int h = 1; h < HEADS; h++) mx = fmaxf(mx, sc[h]);
    float e[HEADS], sum = 0.0f;
#pragma unroll
    for (int h = 0; h < HEADS; h++) { e[h] = __expf(sc[h] - mx); sum += e[h]; }
    const float inv = 1.0f / sum;
#pragma unroll
    for (int h = 0; h < HEADS; h++) attn[(long long)b * HEADS + h] = e[h] * inv;
}

// ---------------------------------------------------------------------------
// context: ctx[b][d] = sum_h attn[b][h]*heads[b][h][d]; writes hi/lo planes
// ---------------------------------------------------------------------------
__global__ __launch_bounds__(256) void context_kernel(
    const __half* __restrict__ headsb, const float* __restrict__ attn,
    u16* __restrict__ ctx_hi, u16* __restrict__ ctx_lo, int MC, int row0)
{
    const int b = blockIdx.x;
    const int d = threadIdx.x * 4;
    float w[HEADS];
#pragma unroll
    for (int h = 0; h < HEADS; h++) w[h] = attn[(long long)b * HEADS + h];
    float4 acc = make_float4(0.f, 0.f, 0.f, 0.f);
#pragma unroll
    for (int h = 0; h < HEADS; h++) {
        const __half2* hp = (const __half2*)(headsb + ((long long)b * HEADS + h) * 1024 + d);
        const float2 f0 = __half22float2(hp[0]);
        const float2 f1 = __half22float2(hp[1]);
        acc.x = fmaf(w[h], f0.x, acc.x);
        acc.y = fmaf(w[h], f0.y, acc.y);
        acc.z = fmaf(w[h], f1.x, acc.z);
        acc.w = fmaf(w[h], f1.y, acc.w);
    }
    uint2 hi, lo;
    splitA4(acc, hi, lo);
    const long long off = ((long long)(d >> 5) * MC + row0 + b) * 32 + (d & 31);
    *(uint2*)(ctx_hi + off) = hi;
    *(uint2*)(ctx_lo + off) = lo;
}

// ---------------------------------------------------------------------------
// fc2: q[b] = sum_d x[b,d]*W2[d] + b2[0]
// ---------------------------------------------------------------------------
__global__ __launch_bounds__(256) void fc2_kernel(
    const float* __restrict__ x, const float* __restrict__ W2,
    const float* __restrict__ b2, float* __restrict__ q)
{
    const int b   = blockIdx.x;
    const int tid = threadIdx.x;
    __shared__ float red[4];

    const float4 xv = *(const float4*)(x + (long long)b * 1024 + tid * 4);
    const float4 wv = *(const float4*)(W2 + tid * 4);
    float p = xv.x * wv.x + xv.y * wv.y + xv.z * wv.z + xv.w * wv.w;
#pragma unroll
    for (int off = 32; off > 0; off >>= 1) p += __shfl_down(p, off, 64);
    if ((tid & 63) == 0) red[tid >> 6] = p;
    __syncthreads();
    if (tid == 0) q[b] = red[0] + red[1] + red[2] + red[3] + b2[0];
}

// ---------------------------------------------------------------------------
extern "C" void kernel_launch(void* const* d_in, const int* in_sizes, int n_in,
                              void* d_out, int out_size, void* d_ws, size_t ws_size,
                              hipStream_t stream)
{
    const float* s        = (const float*)d_in[0];
    const float* a        = (const float*)d_in[1];
    const float* W_enc_in = (const float*)d_in[2];
    const float* b_enc_in = (const float*)d_in[3];
    const float* W_dec_in = (const float*)d_in[4];
    const float* b_dec_in = (const float*)d_in[5];
    const float* W_eh     = (const float*)d_in[6];
    const float* b_eh     = (const float*)d_in[7];
    const float* W_heads  = (const float*)d_in[8];
    const float* b_heads  = (const float*)d_in[9];
    const float* W_dh     = (const float*)d_in[10];
    const float* b_dh     = (const float*)d_in[11];
    const float* W1       = (const float*)d_in[12];
    const float* b1       = (const float*)d_in[13];
    const float* W2       = (const float*)d_in[14];
    const float* b2       = (const float*)d_in[15];
    float* q_out = (float*)d_out;

    // ---- weight plane layout (shorts) -------------------------------------
    u16* P = (u16*)d_ws;
    u16* enc_hi = P; P += 557056;      // 544*1024
    u16* enc_lo = P; P += 557056;
    u16* dec_hi = P; P += 98304;       // 96*1024
    u16* dec_lo = P; P += 98304;
    u16* eh_hi  = P; P += 1048576;
    u16* eh_lo  = P; P += 1048576;
    u16* dh_hi  = P; P += 1048576;
    u16* dh_lo  = P; P += 1048576;
    u16* w1_hi  = P; P += 1048576;
    u16* w1_lo  = P; P += 1048576;
    u16* wh_hi  = P; P += 8388608;     // 8*1024*1024
    u16* wh_lo  = P; P += 8388608;
    char* act = (char*)P;              // 48,758,784 bytes consumed

    const dim3 blk(256);

    // ---- weight conversions ------------------------------------------------
    split_weight_kernel<<<dim3(17, 8, 1), blk, 0, stream>>>(W_enc_in, enc_hi, enc_lo, 544);
    split_weight_kernel<<<dim3(3, 8, 1), blk, 0, stream>>>(W_dec_in, dec_hi, dec_lo, 96);
    split_weight_kernel<<<dim3(32, 8, 1), blk, 0, stream>>>(W_eh, eh_hi, eh_lo, 1024);
    split_weight_kernel<<<dim3(32, 8, 1), blk, 0, stream>>>(W_dh, dh_hi, dh_lo, 1024);
    split_weight_kernel<<<dim3(32, 8, 1), blk, 0, stream>>>(W1, w1_hi, w1_lo, 1024);
    split_weight_kernel<<<dim3(32, 8, 8), blk, 0, stream>>>(W_heads, wh_hi, wh_lo, 1024);

    const bool high = (ws_size >= 150011904ULL);

    if (high) {
        u16*    bufA_hi = (u16*)act;
        u16*    bufA_lo = bufA_hi + 8388608;
        __half* headsb  = (__half*)act;
        u16*    encH_hi = (u16*)(act + 33554432);
        u16*    encH_lo = encH_hi + 8388608;
        float*  decH    = (float*)(act + 2LL * 33554432);
        float*  scoresp = (float*)(act + 3LL * 33554432);
        float*  attnb   = scoresp + 64LL * BC;

        const dim3 gg(8, 64, 1);
        gemm_cvt<0><<<gg, blk, 0, stream>>>(s, 512, 0, a, 128, 512,
            enc_hi, enc_lo, b_enc_in, bufA_hi, bufA_lo, 8192, 544);
        gemm_fast<1, 1><<<gg, blk, 0, stream>>>(bufA_hi, bufA_lo, 8192, 0,
            eh_hi, eh_lo, b_eh, nullptr, encH_hi, encH_lo, 8192, 1024);
        gemm_cvt<0><<<gg, blk, 0, stream>>>(a, 128, 32, a, 128, 1 << 28,
            dec_hi, dec_lo, b_dec_in, bufA_hi, bufA_lo, 8192, 96);
        gemm_fast<1, 0><<<gg, blk, 0, stream>>>(bufA_hi, bufA_lo, 8192, 0,
            dh_hi, dh_lo, b_dh, decH, nullptr, nullptr, 0, 1024);

        for (int c = 0; c < BATCH / BC; c++) {
            heads_kernel<<<dim3(8, BC / 128, 8), blk, 0, stream>>>(
                encH_hi, encH_lo, 8192, c * BC, wh_hi, wh_lo, b_heads,
                decH + (long long)c * BC * 1024, headsb, scoresp);
            softmax_kernel<<<dim3(BC / 256), blk, 0, stream>>>(scoresp, attnb);
            context_kernel<<<dim3(BC), blk, 0, stream>>>(
                headsb, attnb, encH_hi, encH_lo, 8192, c * BC);
        }
        gemm_fast<1, 0><<<gg, blk, 0, stream>>>(encH_hi, encH_lo, 8192, 0,
            w1_hi, w1_lo, b1, decH, nullptr, nullptr, 0, 1024);
        fc2_kernel<<<dim3(BATCH), blk, 0, stream>>>(decH, W2, b2, q_out);
    } else {
        __half* headsb  = (__half*)act;
        u16*    bufA_hi = (u16*)act;
        u16*    bufA_lo = bufA_hi + 2097152;
        u16*    encH_hi = (u16*)(act + 33554432);
        u16*    encH_lo = encH_hi + 2097152;
        float*  decH    = (float*)(act + 33554432 + 8388608);
        float*  scoresp = (float*)(act + 33554432 + 2LL * 8388608);
        float*  attnb   = scoresp + 64LL * BC;

        const dim3 gg(8, BC / 128, 1);
        for (int c = 0; c < BATCH / BC; c++) {
            const float* sC = s + (long long)c * BC * 512;
            const float* aC = a + (long long)c * BC * 128;
            gemm_cvt<0><<<gg, blk, 0, stream>>>(sC, 512, 0, aC, 128, 512,
                enc_hi, enc_lo, b_enc_in, bufA_hi, bufA_lo, BC, 544);
            gemm_fast<1, 1><<<gg, blk, 0, stream>>>(bufA_hi, bufA_lo, BC, 0,
                eh_hi, eh_lo, b_eh, nullptr, encH_hi, encH_lo, BC, 1024);
            gemm_cvt<0><<<gg, blk, 0, stream>>>(aC, 128, 32, aC, 128, 1 << 28,
                dec_hi, dec_lo, b_dec_in, bufA_hi, bufA_lo, BC, 96);
            gemm_fast<1, 0><<<gg, blk, 0, stream>>>(bufA_hi, bufA_lo, BC, 0,
                dh_hi, dh_lo, b_dh, decH, nullptr, nullptr, 0, 1024);
            heads_kernel<<<dim3(8, BC / 128, 8), blk, 0, stream>>>(
                encH_hi, encH_lo, BC, 0, wh_hi, wh_lo, b_heads,
                decH, headsb, scoresp);
            softmax_kernel<<<dim3(BC / 256), blk, 0, stream>>>(scoresp, attnb);
            context_kernel<<<dim3(BC), blk, 0, stream>>>(
                headsb, attnb, encH_hi, encH_lo, BC, 0);
            gemm_fast<1, 0><<<gg, blk, 0, stream>>>(encH_hi, encH_lo, BC, 0,
                w1_hi, w1_lo, b1, decH, nullptr, nullptr, 0, 1024);
            fc2_kernel<<<dim3(BC), blk, 0, stream>>>(decH, W2, b2, q_out + (long long)c * BC);
        }
    }
}